// Round 2
// baseline (1164.213 us; speedup 1.0000x reference)
//
#include <hip/hip_runtime.h>
#include <math.h>

#define N_DIM 1000
#define P_DIM 50000
#define Z_DIM 10
#define L_DIM 5
#define NT 256
#define NB 196          // ceil(50000/256); also persistent grid size (<=256 CUs)
#define NSPLIT 4
#define NCHUNK 250      // N_DIM / NSPLIT
#define NSTEPS 50       // Z_DIM * L_DIM
#define NEG_BIG (-3.0e38f)

// ---- workspace layout (floats) ----
constexpr size_t ZP      = (size_t)Z_DIM * P_DIM;      // 500000
constexpr size_t OFF_ZTR = 0;                          // [Z][P]
constexpr size_t OFF_W   = ZP;                         // [Z][P]
constexpr size_t OFF_ZZ  = 2 * ZP;                     // [Z*Z], reserve 128 (even)
constexpr size_t OFF_CNT = 2 * ZP + 128;               // 64 x u32 (even float idx)
constexpr size_t OFF_PART= OFF_CNT + 64;               // 2 x NB x u64 (8B aligned)

// ---- output layout (floats) ----
constexpr size_t OUT_VW = (size_t)L_DIM * Z_DIM * P_DIM;          // 2,500,000
constexpr size_t OUT_AL = OUT_VW + (size_t)L_DIM * Z_DIM;         // 2,500,050

__device__ inline unsigned long long pack2(float m, float e) {
    return (unsigned long long)__float_as_uint(m) |
           ((unsigned long long)__float_as_uint(e) << 32);
}

// Online-softmax merge. NEG_BIG (not -INF) avoids NaN from inf-inf.
__device__ inline void online_merge(float& m, float& e, float m2, float e2) {
    float M = fmaxf(m, m2);
    e = e * __expf(m - M) + e2 * __expf(m2 - M);
    m = M;
}

// Block-wide online-softmax reduction; all threads exit with merged (m,e).
__device__ inline void block_merge(float& m, float& e, float* sm, float* se, float* bro) {
    int lane = threadIdx.x & 63;
    int wid  = threadIdx.x >> 6;
    #pragma unroll
    for (int off = 32; off > 0; off >>= 1) {
        float m2 = __shfl_xor(m, off);
        float e2 = __shfl_xor(e, off);
        online_merge(m, e, m2, e2);
    }
    if (lane == 0) { sm[wid] = m; se[wid] = e; }
    __syncthreads();
    if (threadIdx.x == 0) {
        float M = sm[0], E = se[0];
        #pragma unroll
        for (int w = 1; w < NT / 64; w++) online_merge(M, E, sm[w], se[w]);
        bro[0] = M; bro[1] = E;
    }
    __syncthreads();
    m = bro[0]; e = bro[1];
}

// mean_zz[i][j] = sum_n mean_z[n,i]*mean_z[n,j] + N*var_z[i,j]
__global__ __launch_bounds__(256) void init_zz(const float* __restrict__ mean_z,
                                               const float* __restrict__ var_z,
                                               float* __restrict__ ws) {
    float* zz = ws + OFF_ZZ;
    int i = blockIdx.x / Z_DIM, j = blockIdx.x % Z_DIM;
    float s = 0.f;
    for (int n = threadIdx.x; n < N_DIM; n += 256)
        s += mean_z[n * Z_DIM + i] * mean_z[n * Z_DIM + j];
    #pragma unroll
    for (int off = 32; off > 0; off >>= 1) s += __shfl_xor(s, off);
    __shared__ float ls[4];
    if ((threadIdx.x & 63) == 0) ls[threadIdx.x >> 6] = s;
    __syncthreads();
    if (threadIdx.x == 0) {
        float t = ls[0] + ls[1] + ls[2] + ls[3];
        zz[blockIdx.x] = t + (float)N_DIM * var_z[blockIdx.x];
    }
}

// ZtR[z][p] += chunk-sum of mean_z[n,z]*data[n,p]  (atomic, 4 n-chunks)
// W0[z][p]  = sum_l mean_w[l,z,p]*alpha[l,z,p]     (y==0 only)
__global__ __launch_bounds__(NT) void precompute_big(const float* __restrict__ data,
                                                     const float* __restrict__ mean_z,
                                                     const float* __restrict__ mw0,
                                                     const float* __restrict__ al0,
                                                     float* __restrict__ ws) {
    float* ZtR = ws + OFF_ZTR;
    float* W   = ws + OFF_W;
    __shared__ float mzs[NCHUNK * Z_DIM];   // 10 KB
    int n0 = blockIdx.y * NCHUNK;
    for (int i = threadIdx.x; i < NCHUNK * Z_DIM; i += NT)
        mzs[i] = mean_z[n0 * Z_DIM + i];
    __syncthreads();
    int p = blockIdx.x * NT + threadIdx.x;
    if (p >= P_DIM) return;

    float acc[Z_DIM];
    #pragma unroll
    for (int z = 0; z < Z_DIM; z++) acc[z] = 0.f;
    for (int r = 0; r < NCHUNK; r++) {
        float d = data[(size_t)(n0 + r) * P_DIM + p];
        #pragma unroll
        for (int z = 0; z < Z_DIM; z++) acc[z] += mzs[r * Z_DIM + z] * d;
    }
    #pragma unroll
    for (int z = 0; z < Z_DIM; z++) atomicAdd(&ZtR[(size_t)z * P_DIM + p], acc[z]);

    if (blockIdx.y == 0) {
        #pragma unroll
        for (int z = 0; z < Z_DIM; z++) {
            float w = 0.f;
            #pragma unroll
            for (int l = 0; l < L_DIM; l++) {
                size_t io = ((size_t)l * Z_DIM + z) * P_DIM + p;
                w += mw0[io] * al0[io];
            }
            W[(size_t)z * P_DIM + p] = w;
        }
    }
}

// Persistent kernel: all 50 sequential (k,l) steps with one device-scope
// barrier round-trip per step. Thread owns one p; W/Wk/RtZ/logits in regs.
__global__ __launch_bounds__(NT) void fused_steps(const float* __restrict__ mw0,
                                                  const float* __restrict__ al0,
                                                  const float* __restrict__ pi,
                                                  const float* __restrict__ tau0,
                                                  const float* __restrict__ taup,
                                                  float* __restrict__ ws,
                                                  float* __restrict__ out) {
    float* ZtR = ws + OFF_ZTR;
    float* Wg  = ws + OFF_W;
    float* zz  = ws + OFF_ZZ;
    unsigned int* cnt       = (unsigned int*)(ws + OFF_CNT);
    unsigned long long* part= (unsigned long long*)(ws + OFF_PART);

    float* out_mw = out;
    float* out_vw = out + OUT_VW;
    float* out_al = out + OUT_AL;

    __shared__ float sm[NT / 64], se[NT / 64], bro[2];

    int tid = threadIdx.x;
    int blk = blockIdx.x;
    int p = blk * NT + tid;
    bool valid = p < P_DIM;
    float tau = taup[0];

    float W[Z_DIM];
    #pragma unroll
    for (int z = 0; z < Z_DIM; z++)
        W[z] = valid ? Wg[(size_t)z * P_DIM + p] : 0.f;

    // prefetched operands for the *current* step
    float nx_mw = 0.f, nx_al = 0.f, nx_ztr = 0.f, nx_pi = 1.f;
    if (valid) {
        nx_mw  = mw0[p];
        nx_al  = al0[p];
        nx_ztr = ZtR[p];
        nx_pi  = pi[p];
    }

    float wk = 0.f, r = 0.f, lp = 0.f;
    int k = 0, l = 0;
    for (int s = 0; s < NSTEPS; s++) {
        // uniform per-step scalars (scalar loads; zz/tau0 tiny, L2-hot)
        float Ezz   = zz[k * Z_DIM + k];
        float t0v   = tau0[l * Z_DIM + k];
        float u_var = 1.f / (tau * Ezz + t0v);
        float s2    = 1.f / (Ezz * tau);
        float s0inv = 1.f / t0v;
        float cq    = 0.5f * (tau / Ezz) * (s0inv / (s2 + s0inv));

        if (l == 0) {
            r = nx_ztr;
            #pragma unroll
            for (int j = 0; j < Z_DIM; j++)
                if (j != k) r -= zz[k * Z_DIM + j] * W[j];
            wk = W[k];
            lp = __logf(nx_pi);
        }

        size_t io = ((size_t)l * Z_DIM + k) * P_DIM + p;
        float wkl = wk - nx_mw * nx_al;
        float E   = r - Ezz * wkl;
        float um  = tau * u_var * E;
        float lgt = valid ? (lp + cq * E * E) : NEG_BIG;
        if (valid) out_mw[io] = um;
        if (blk == 0 && tid == 0) out_vw[l * Z_DIM + k] = u_var;

        float m = lgt, e = valid ? 1.f : 0.f;
        block_merge(m, e, sm, se, bro);

        // prefetch next step's operands BEFORE the barrier (hides under spin)
        int l2 = l + 1, k2 = k;
        if (l2 == L_DIM) { l2 = 0; k2++; }
        if (s + 1 < NSTEPS && valid) {
            size_t io2 = ((size_t)l2 * Z_DIM + k2) * P_DIM + p;
            nx_mw = mw0[io2];
            nx_al = al0[io2];
            if (l2 == 0) {
                nx_ztr = ZtR[(size_t)k2 * P_DIM + p];
                nx_pi  = pi[(size_t)k2 * P_DIM + p];
            }
        }

        unsigned long long* pbuf = part + (size_t)(s & 1) * NB;
        if (tid == 0) {
            __hip_atomic_store(&pbuf[blk], pack2(m, e),
                               __ATOMIC_RELAXED, __HIP_MEMORY_SCOPE_AGENT);
            __hip_atomic_fetch_add(&cnt[s], 1u,
                                   __ATOMIC_RELEASE, __HIP_MEMORY_SCOPE_AGENT);
            while (__hip_atomic_load(&cnt[s], __ATOMIC_ACQUIRE,
                                     __HIP_MEMORY_SCOPE_AGENT) < (unsigned)NB)
                __builtin_amdgcn_s_sleep(1);
        }
        __syncthreads();

        // every block merges all 196 partials locally (single round-trip)
        float mm = NEG_BIG, ee = 0.f;
        if (tid < NB) {
            unsigned long long v = __hip_atomic_load(&pbuf[tid], __ATOMIC_ACQUIRE,
                                                     __HIP_MEMORY_SCOPE_AGENT);
            mm = __uint_as_float((unsigned)v);
            ee = __uint_as_float((unsigned)(v >> 32));
        }
        block_merge(mm, ee, sm, se, bro);

        if (valid) {
            float a = __expf(lgt - mm) / ee;
            out_al[io] = a;
            wk = wkl + um * a;
            if (l == L_DIM - 1) W[k] = wk;   // register-only W update
        }
        l = l2; k = k2;
    }
}

extern "C" void kernel_launch(void* const* d_in, const int* in_sizes, int n_in,
                              void* d_out, int out_size, void* d_ws, size_t ws_size,
                              hipStream_t stream) {
    (void)in_sizes; (void)n_in; (void)out_size; (void)ws_size;
    const float* data   = (const float*)d_in[0];
    const float* mean_z = (const float*)d_in[1];
    const float* var_z  = (const float*)d_in[2];
    const float* mw0    = (const float*)d_in[3];
    // d_in[4] var_w: unused (fully overwritten in output)
    const float* al0    = (const float*)d_in[5];
    const float* tau0   = (const float*)d_in[6];
    const float* pi     = (const float*)d_in[7];
    const float* taup   = (const float*)d_in[8];
    float* out = (float*)d_out;
    float* ws  = (float*)d_ws;

    // zero ZtR accumulator + barrier counters (ws poisoned 0xAA each call)
    hipMemsetAsync(ws, 0, ZP * sizeof(float), stream);
    hipMemsetAsync((char*)d_ws + OFF_CNT * sizeof(float), 0, 64 * sizeof(unsigned int), stream);

    init_zz<<<Z_DIM * Z_DIM, 256, 0, stream>>>(mean_z, var_z, ws);
    precompute_big<<<dim3(NB, NSPLIT), NT, 0, stream>>>(data, mean_z, mw0, al0, ws);
    fused_steps<<<NB, NT, 0, stream>>>(mw0, al0, pi, tau0, taup, ws, out);
}

// Round 3
// 607.740 us; speedup vs baseline: 1.9156x; 1.9156x over previous
//
#include <hip/hip_runtime.h>
#include <math.h>

#define N_DIM 1000
#define P_DIM 50000
#define Z_DIM 10
#define L_DIM 5
#define NT 256
#define NB 196          // ceil(50000/256); persistent grid (<=256 CUs, co-resident)
#define NSPLIT 4
#define NCHUNK 250      // N_DIM / NSPLIT
#define NSTEPS 50       // Z_DIM * L_DIM
#define NEG_BIG (-3.0e38f)

// ---- workspace layout (floats) ----
constexpr size_t ZP      = (size_t)Z_DIM * P_DIM;      // 500000
constexpr size_t OFF_ZTR = 0;                          // [Z][P]
constexpr size_t OFF_W   = ZP;                         // [Z][P]
constexpr size_t OFF_ZZ  = 2 * ZP;                     // [Z*Z], reserve 128 (even)
constexpr size_t OFF_CNT = 2 * ZP + 128;               // NSTEPS+pad x u32
constexpr size_t OFF_PART= OFF_CNT + 64;               // 2 x NB x u64 (8B aligned)

// ---- output layout (floats) ----
constexpr size_t OUT_VW = (size_t)L_DIM * Z_DIM * P_DIM;          // 2,500,000
constexpr size_t OUT_AL = OUT_VW + (size_t)L_DIM * Z_DIM;         // 2,500,050

__device__ inline unsigned long long pack2(float m, float e) {
    return (unsigned long long)__float_as_uint(m) |
           ((unsigned long long)__float_as_uint(e) << 32);
}

// Online-softmax merge. NEG_BIG (not -INF) avoids NaN from inf-inf.
__device__ inline void online_merge(float& m, float& e, float m2, float e2) {
    float M = fmaxf(m, m2);
    e = e * __expf(m - M) + e2 * __expf(m2 - M);
    m = M;
}

// Block-wide online-softmax reduction; all threads exit with merged (m,e).
__device__ inline void block_merge(float& m, float& e, float* sm, float* se, float* bro) {
    int lane = threadIdx.x & 63;
    int wid  = threadIdx.x >> 6;
    #pragma unroll
    for (int off = 32; off > 0; off >>= 1) {
        float m2 = __shfl_xor(m, off);
        float e2 = __shfl_xor(e, off);
        online_merge(m, e, m2, e2);
    }
    if (lane == 0) { sm[wid] = m; se[wid] = e; }
    __syncthreads();
    if (threadIdx.x == 0) {
        float M = sm[0], E = se[0];
        #pragma unroll
        for (int w = 1; w < NT / 64; w++) online_merge(M, E, sm[w], se[w]);
        bro[0] = M; bro[1] = E;
    }
    __syncthreads();
    m = bro[0]; e = bro[1];
}

// mean_zz[i][j] = sum_n mean_z[n,i]*mean_z[n,j] + N*var_z[i,j]
__global__ __launch_bounds__(256) void init_zz(const float* __restrict__ mean_z,
                                               const float* __restrict__ var_z,
                                               float* __restrict__ ws) {
    float* zz = ws + OFF_ZZ;
    int i = blockIdx.x / Z_DIM, j = blockIdx.x % Z_DIM;
    float s = 0.f;
    for (int n = threadIdx.x; n < N_DIM; n += 256)
        s += mean_z[n * Z_DIM + i] * mean_z[n * Z_DIM + j];
    #pragma unroll
    for (int off = 32; off > 0; off >>= 1) s += __shfl_xor(s, off);
    __shared__ float ls[4];
    if ((threadIdx.x & 63) == 0) ls[threadIdx.x >> 6] = s;
    __syncthreads();
    if (threadIdx.x == 0) {
        float t = ls[0] + ls[1] + ls[2] + ls[3];
        zz[blockIdx.x] = t + (float)N_DIM * var_z[blockIdx.x];
    }
}

// ZtR[z][p] += chunk-sum of mean_z[n,z]*data[n,p]  (atomic, 4 n-chunks)
// W0[z][p]  = sum_l mean_w[l,z,p]*alpha[l,z,p]     (y==0 only)
__global__ __launch_bounds__(NT) void precompute_big(const float* __restrict__ data,
                                                     const float* __restrict__ mean_z,
                                                     const float* __restrict__ mw0,
                                                     const float* __restrict__ al0,
                                                     float* __restrict__ ws) {
    float* ZtR = ws + OFF_ZTR;
    float* W   = ws + OFF_W;
    __shared__ float mzs[NCHUNK * Z_DIM];   // 10 KB
    int n0 = blockIdx.y * NCHUNK;
    for (int i = threadIdx.x; i < NCHUNK * Z_DIM; i += NT)
        mzs[i] = mean_z[n0 * Z_DIM + i];
    __syncthreads();
    int p = blockIdx.x * NT + threadIdx.x;
    if (p >= P_DIM) return;

    float acc[Z_DIM];
    #pragma unroll
    for (int z = 0; z < Z_DIM; z++) acc[z] = 0.f;
    for (int r = 0; r < NCHUNK; r++) {
        float d = data[(size_t)(n0 + r) * P_DIM + p];
        #pragma unroll
        for (int z = 0; z < Z_DIM; z++) acc[z] += mzs[r * Z_DIM + z] * d;
    }
    #pragma unroll
    for (int z = 0; z < Z_DIM; z++) atomicAdd(&ZtR[(size_t)z * P_DIM + p], acc[z]);

    if (blockIdx.y == 0) {
        #pragma unroll
        for (int z = 0; z < Z_DIM; z++) {
            float w = 0.f;
            #pragma unroll
            for (int l = 0; l < L_DIM; l++) {
                size_t io = ((size_t)l * Z_DIM + z) * P_DIM + p;
                w += mw0[io] * al0[io];
            }
            W[(size_t)z * P_DIM + p] = w;
        }
    }
}

// Persistent kernel: all 50 sequential (k,l) steps. One relaxed-atomic
// barrier round-trip per step; NO release/acquire (no buffer_wbl2/buffer_inv).
__global__ __launch_bounds__(NT) void fused_steps(const float* __restrict__ mw0,
                                                  const float* __restrict__ al0,
                                                  const float* __restrict__ pi,
                                                  const float* __restrict__ tau0,
                                                  const float* __restrict__ taup,
                                                  float* __restrict__ ws,
                                                  float* __restrict__ out) {
    float* ZtR = ws + OFF_ZTR;
    float* Wg  = ws + OFF_W;
    float* zz  = ws + OFF_ZZ;
    unsigned int* cnt        = (unsigned int*)(ws + OFF_CNT);
    unsigned long long* part = (unsigned long long*)(ws + OFF_PART);

    float* out_mw = out;
    float* out_vw = out + OUT_VW;
    float* out_al = out + OUT_AL;

    __shared__ float sm[NT / 64], se[NT / 64], bro[2];

    int tid = threadIdx.x;
    int blk = blockIdx.x;
    int p = blk * NT + tid;
    bool valid = p < P_DIM;
    float tau = taup[0];

    float W[Z_DIM];
    #pragma unroll
    for (int z = 0; z < Z_DIM; z++)
        W[z] = valid ? Wg[(size_t)z * P_DIM + p] : 0.f;

    // prefetched operands for the *current* step
    float nx_mw = 0.f, nx_al = 0.f, nx_ztr = 0.f, nx_pi = 1.f;
    if (valid) {
        nx_mw  = mw0[p];
        nx_al  = al0[p];
        nx_ztr = ZtR[p];
        nx_pi  = pi[p];
    }

    float wk = 0.f, r = 0.f, lp = 0.f;
    int k = 0, l = 0;
    for (int s = 0; s < NSTEPS; s++) {
        // uniform per-step scalars (tiny, L2-hot)
        float Ezz   = zz[k * Z_DIM + k];
        float t0v   = tau0[l * Z_DIM + k];
        float u_var = 1.f / (tau * Ezz + t0v);
        float s2    = 1.f / (Ezz * tau);
        float s0inv = 1.f / t0v;
        float cq    = 0.5f * (tau / Ezz) * (s0inv / (s2 + s0inv));

        if (l == 0) {
            r = nx_ztr;
            #pragma unroll
            for (int j = 0; j < Z_DIM; j++)
                if (j != k) r -= zz[k * Z_DIM + j] * W[j];
            wk = W[k];
            lp = __logf(nx_pi);
        }

        size_t io = ((size_t)l * Z_DIM + k) * P_DIM + p;
        float wkl = wk - nx_mw * nx_al;
        float E   = r - Ezz * wkl;
        float um  = tau * u_var * E;
        float lgt = valid ? (lp + cq * E * E) : NEG_BIG;
        if (valid) out_mw[io] = um;
        if (blk == 0 && tid == 0) out_vw[l * Z_DIM + k] = u_var;

        float m = lgt, e = valid ? 1.f : 0.f;
        block_merge(m, e, sm, se, bro);

        // prefetch next step's operands BEFORE the barrier (hides under spin)
        int l2 = l + 1, k2 = k;
        if (l2 == L_DIM) { l2 = 0; k2++; }
        if (s + 1 < NSTEPS && valid) {
            size_t io2 = ((size_t)l2 * Z_DIM + k2) * P_DIM + p;
            nx_mw = mw0[io2];
            nx_al = al0[io2];
            if (l2 == 0) {
                nx_ztr = ZtR[(size_t)k2 * P_DIM + p];
                nx_pi  = pi[(size_t)k2 * P_DIM + p];
            }
        }

        unsigned long long* pbuf = part + (size_t)(s & 1) * NB;
        if (tid == 0) {
            // data word: relaxed agent atomic (sc1 -> coherence point, no flush)
            __hip_atomic_store(&pbuf[blk], pack2(m, e),
                               __ATOMIC_RELAXED, __HIP_MEMORY_SCOPE_AGENT);
            // order data before signal: drain vm counter only (no cache ops)
            __atomic_signal_fence(__ATOMIC_SEQ_CST);
            __builtin_amdgcn_s_waitcnt(0);
            __atomic_signal_fence(__ATOMIC_SEQ_CST);
            // fire-and-forget increment (no return value -> non-blocking)
            __hip_atomic_fetch_add(&cnt[s], 1u,
                                   __ATOMIC_RELAXED, __HIP_MEMORY_SCOPE_AGENT);
            while (__hip_atomic_load(&cnt[s], __ATOMIC_RELAXED,
                                     __HIP_MEMORY_SCOPE_AGENT) < (unsigned)NB)
                __builtin_amdgcn_s_sleep(2);
        }
        __syncthreads();

        // every block merges all 196 partials locally (single round-trip)
        float mm = NEG_BIG, ee = 0.f;
        if (tid < NB) {
            unsigned long long v = __hip_atomic_load(&pbuf[tid], __ATOMIC_RELAXED,
                                                     __HIP_MEMORY_SCOPE_AGENT);
            mm = __uint_as_float((unsigned)v);
            ee = __uint_as_float((unsigned)(v >> 32));
        }
        block_merge(mm, ee, sm, se, bro);

        if (valid) {
            float a = __expf(lgt - mm) / ee;
            out_al[io] = a;
            wk = wkl + um * a;
            if (l == L_DIM - 1) W[k] = wk;   // register-only W update
        }
        l = l2; k = k2;
    }
}

extern "C" void kernel_launch(void* const* d_in, const int* in_sizes, int n_in,
                              void* d_out, int out_size, void* d_ws, size_t ws_size,
                              hipStream_t stream) {
    (void)in_sizes; (void)n_in; (void)out_size; (void)ws_size;
    const float* data   = (const float*)d_in[0];
    const float* mean_z = (const float*)d_in[1];
    const float* var_z  = (const float*)d_in[2];
    const float* mw0    = (const float*)d_in[3];
    // d_in[4] var_w: unused (fully overwritten in output)
    const float* al0    = (const float*)d_in[5];
    const float* tau0   = (const float*)d_in[6];
    const float* pi     = (const float*)d_in[7];
    const float* taup   = (const float*)d_in[8];
    float* out = (float*)d_out;
    float* ws  = (float*)d_ws;

    // zero ZtR accumulator + barrier counters (ws poisoned 0xAA each call)
    hipMemsetAsync(ws, 0, ZP * sizeof(float), stream);
    hipMemsetAsync((char*)d_ws + OFF_CNT * sizeof(float), 0, 64 * sizeof(unsigned int), stream);

    init_zz<<<Z_DIM * Z_DIM, 256, 0, stream>>>(mean_z, var_z, ws);
    precompute_big<<<dim3(NB, NSPLIT), NT, 0, stream>>>(data, mean_z, mw0, al0, ws);
    fused_steps<<<NB, NT, 0, stream>>>(mw0, al0, pi, tau0, taup, ws, out);
}